// Round 4
// baseline (76.979 us; speedup 1.0000x reference)
//
#include <hip/hip_runtime.h>

// LIF spike recurrence over time axis.
// x: [B=32, T=10, C=128, H=32, W=32] fp32 -> spikes same shape fp32.
// mem_t = tau*mem_{t-1} + x_t; spike = (mem_t > thresh); mem_t *= (1-spike).
//
// R4: each lane owns 32B CONTIGUOUS (two adjacent float4s) instead of two
// columns 256KB apart -> each wave's loads form one 2KB contiguous segment
// per t-step (better DRAM page locality). nt load/store kept (pure stream),
// full unroll so compiler can hoist/pipeline all 20 loads (MLP).

typedef float f32x4 __attribute__((ext_vector_type(4)));

#define LIF_T 10
#define LIF_INNER4 32768       // C*H*W/4 per (b,t) slab, in float4 units
#define LIF_TAU 0.5f
#define LIF_THRESH 1.0f

__global__ void __launch_bounds__(256) lif_kernel(const f32x4* __restrict__ x,
                                                  f32x4* __restrict__ y) {
    // each thread: 2 adjacent float4s => pair index p in [0, INNER4/2)
    const int p = blockIdx.x * blockDim.x + threadIdx.x;
    const int b = blockIdx.y;
    const size_t base = (size_t)b * LIF_T * LIF_INNER4 + (size_t)p * 2;

    f32x4 m0 = (f32x4)(0.f);
    f32x4 m1 = (f32x4)(0.f);

#pragma unroll
    for (int t = 0; t < LIF_T; ++t) {
        const size_t i0 = base + (size_t)t * LIF_INNER4;
        f32x4 x0 = __builtin_nontemporal_load(&x[i0]);
        f32x4 x1 = __builtin_nontemporal_load(&x[i0 + 1]);

        m0 = m0 * LIF_TAU + x0;
        m1 = m1 * LIF_TAU + x1;

        f32x4 s0, s1;
        s0.x = (m0.x > LIF_THRESH) ? 1.f : 0.f;
        s0.y = (m0.y > LIF_THRESH) ? 1.f : 0.f;
        s0.z = (m0.z > LIF_THRESH) ? 1.f : 0.f;
        s0.w = (m0.w > LIF_THRESH) ? 1.f : 0.f;
        s1.x = (m1.x > LIF_THRESH) ? 1.f : 0.f;
        s1.y = (m1.y > LIF_THRESH) ? 1.f : 0.f;
        s1.z = (m1.z > LIF_THRESH) ? 1.f : 0.f;
        s1.w = (m1.w > LIF_THRESH) ? 1.f : 0.f;

        __builtin_nontemporal_store(s0, &y[i0]);
        __builtin_nontemporal_store(s1, &y[i0 + 1]);

        // hard reset: mem <- (1 - spike) * mem
        m0.x = (s0.x > 0.f) ? 0.f : m0.x;
        m0.y = (s0.y > 0.f) ? 0.f : m0.y;
        m0.z = (s0.z > 0.f) ? 0.f : m0.z;
        m0.w = (s0.w > 0.f) ? 0.f : m0.w;
        m1.x = (s1.x > 0.f) ? 0.f : m1.x;
        m1.y = (s1.y > 0.f) ? 0.f : m1.y;
        m1.z = (s1.z > 0.f) ? 0.f : m1.z;
        m1.w = (s1.w > 0.f) ? 0.f : m1.w;
    }
}

extern "C" void kernel_launch(void* const* d_in, const int* in_sizes, int n_in,
                              void* d_out, int out_size, void* d_ws, size_t ws_size,
                              hipStream_t stream) {
    const f32x4* x = (const f32x4*)d_in[0];
    f32x4* y = (f32x4*)d_out;

    dim3 block(256, 1, 1);
    dim3 grid((LIF_INNER4 / 2) / 256, 32, 1);   // 64 x 32 = 2048 blocks
    lif_kernel<<<grid, block, 0, stream>>>(x, y);
}

// Round 5
// 62.258 us; speedup vs baseline: 1.2364x; 1.2364x over previous
//
#include <hip/hip_runtime.h>

// LIF spike recurrence over time axis.
// x: [B=32, T=10, C=128, H=32, W=32] fp32 -> spikes same shape fp32.
// mem_t = tau*mem_{t-1} + x_t; spike = (mem_t > thresh); mem_t *= (1-spike).
//
// R5: back to R3's per-instruction-coalesced pattern (consecutive lanes ->
// consecutive float4s; R4's per-lane-contiguous variant halved effective
// per-instruction density and regressed 28%). Changes vs R3:
//   - 4 independent chains/thread (was 2): 4x outstanding loads per wave
//   - chain offsets = 256 float4 (one block width, 4KB) instead of 256KB:
//     each block's 4 loads/t cover one contiguous 16KB region (page locality)
//   - nt load/store kept (pure 335MB stream, no reuse)

typedef float f32x4 __attribute__((ext_vector_type(4)));

#define LIF_T 10
#define LIF_INNER4 32768       // C*H*W/4 per (b,t) slab, in float4 units
#define LIF_TAU 0.5f
#define LIF_THRESH 1.0f

__device__ __forceinline__ f32x4 lif_spike(const f32x4& m) {
    f32x4 s;
    s.x = (m.x > LIF_THRESH) ? 1.f : 0.f;
    s.y = (m.y > LIF_THRESH) ? 1.f : 0.f;
    s.z = (m.z > LIF_THRESH) ? 1.f : 0.f;
    s.w = (m.w > LIF_THRESH) ? 1.f : 0.f;
    return s;
}

__device__ __forceinline__ void lif_reset(f32x4& m, const f32x4& s) {
    m.x = (s.x > 0.f) ? 0.f : m.x;
    m.y = (s.y > 0.f) ? 0.f : m.y;
    m.z = (s.z > 0.f) ? 0.f : m.z;
    m.w = (s.w > 0.f) ? 0.f : m.w;
}

__global__ void __launch_bounds__(256) lif_kernel(const f32x4* __restrict__ x,
                                                  f32x4* __restrict__ y) {
    // block covers 4*256 = 1024 contiguous float4 (16KB); 4 chains per thread
    // at offsets 0,256,512,768 within the block's region.
    const int b = blockIdx.y;
    const size_t base = (size_t)b * LIF_T * LIF_INNER4
                      + (size_t)blockIdx.x * 1024 + threadIdx.x;

    f32x4 m0 = (f32x4)(0.f), m1 = (f32x4)(0.f);
    f32x4 m2 = (f32x4)(0.f), m3 = (f32x4)(0.f);

#pragma unroll
    for (int t = 0; t < LIF_T; ++t) {
        const size_t i0 = base + (size_t)t * LIF_INNER4;
        f32x4 x0 = __builtin_nontemporal_load(&x[i0]);
        f32x4 x1 = __builtin_nontemporal_load(&x[i0 + 256]);
        f32x4 x2 = __builtin_nontemporal_load(&x[i0 + 512]);
        f32x4 x3 = __builtin_nontemporal_load(&x[i0 + 768]);

        m0 = m0 * LIF_TAU + x0;
        m1 = m1 * LIF_TAU + x1;
        m2 = m2 * LIF_TAU + x2;
        m3 = m3 * LIF_TAU + x3;

        f32x4 s0 = lif_spike(m0);
        f32x4 s1 = lif_spike(m1);
        f32x4 s2 = lif_spike(m2);
        f32x4 s3 = lif_spike(m3);

        __builtin_nontemporal_store(s0, &y[i0]);
        __builtin_nontemporal_store(s1, &y[i0 + 256]);
        __builtin_nontemporal_store(s2, &y[i0 + 512]);
        __builtin_nontemporal_store(s3, &y[i0 + 768]);

        lif_reset(m0, s0);
        lif_reset(m1, s1);
        lif_reset(m2, s2);
        lif_reset(m3, s3);
    }
}

extern "C" void kernel_launch(void* const* d_in, const int* in_sizes, int n_in,
                              void* d_out, int out_size, void* d_ws, size_t ws_size,
                              hipStream_t stream) {
    const f32x4* x = (const f32x4*)d_in[0];
    f32x4* y = (f32x4*)d_out;

    dim3 block(256, 1, 1);
    dim3 grid(LIF_INNER4 / 1024, 32, 1);   // 32 x 32 = 1024 blocks
    lif_kernel<<<grid, block, 0, stream>>>(x, y);
}

// Round 6
// 59.336 us; speedup vs baseline: 1.2973x; 1.0492x over previous
//
#include <hip/hip_runtime.h>

// LIF spike recurrence over time axis.
// x: [B=32, T=10, C=128, H=32, W=32] fp32 -> spikes same shape fp32.
// mem_t = tau*mem_{t-1} + x_t; spike = (mem_t > thresh); mem_t *= (1-spike).
//
// R6: R3 structure (2 chains/thread at +HALF offset, 2048 blocks, nt
// load/store, per-instruction coalesced) + LOADS-FIRST scheduling: all
// T*2 = 20 float4 loads issue before any compute/store, maximizing
// per-thread read MLP (~80 VGPRs of x in flight; still >=4 waves/SIMD).

typedef float f32x4 __attribute__((ext_vector_type(4)));

#define LIF_T 10
#define LIF_INNER4 32768       // C*H*W/4 per (b,t) slab, in float4 units
#define LIF_HALF 16384
#define LIF_TAU 0.5f
#define LIF_THRESH 1.0f

__device__ __forceinline__ f32x4 lif_spike(const f32x4& m) {
    f32x4 s;
    s.x = (m.x > LIF_THRESH) ? 1.f : 0.f;
    s.y = (m.y > LIF_THRESH) ? 1.f : 0.f;
    s.z = (m.z > LIF_THRESH) ? 1.f : 0.f;
    s.w = (m.w > LIF_THRESH) ? 1.f : 0.f;
    return s;
}

__device__ __forceinline__ void lif_reset(f32x4& m, const f32x4& s) {
    m.x = (s.x > 0.f) ? 0.f : m.x;
    m.y = (s.y > 0.f) ? 0.f : m.y;
    m.z = (s.z > 0.f) ? 0.f : m.z;
    m.w = (s.w > 0.f) ? 0.f : m.w;
}

__global__ void __launch_bounds__(256) lif_kernel(const f32x4* __restrict__ x,
                                                  f32x4* __restrict__ y) {
    const int i = blockIdx.x * blockDim.x + threadIdx.x;   // 0 .. HALF-1
    const int b = blockIdx.y;
    const size_t base0 = (size_t)b * LIF_T * LIF_INNER4 + i;
    const size_t base1 = base0 + LIF_HALF;

    // ---- phase 1: issue ALL loads (fully unrolled, static indices) ----
    f32x4 x0[LIF_T], x1[LIF_T];
#pragma unroll
    for (int t = 0; t < LIF_T; ++t) {
        x0[t] = __builtin_nontemporal_load(&x[base0 + (size_t)t * LIF_INNER4]);
        x1[t] = __builtin_nontemporal_load(&x[base1 + (size_t)t * LIF_INNER4]);
    }

    // ---- phase 2: recurrence + stores ----
    f32x4 m0 = (f32x4)(0.f), m1 = (f32x4)(0.f);
#pragma unroll
    for (int t = 0; t < LIF_T; ++t) {
        const size_t i0 = base0 + (size_t)t * LIF_INNER4;
        const size_t i1 = base1 + (size_t)t * LIF_INNER4;

        m0 = m0 * LIF_TAU + x0[t];
        m1 = m1 * LIF_TAU + x1[t];

        f32x4 s0 = lif_spike(m0);
        f32x4 s1 = lif_spike(m1);

        __builtin_nontemporal_store(s0, &y[i0]);
        __builtin_nontemporal_store(s1, &y[i1]);

        lif_reset(m0, s0);
        lif_reset(m1, s1);
    }
}

extern "C" void kernel_launch(void* const* d_in, const int* in_sizes, int n_in,
                              void* d_out, int out_size, void* d_ws, size_t ws_size,
                              hipStream_t stream) {
    const f32x4* x = (const f32x4*)d_in[0];
    f32x4* y = (f32x4*)d_out;

    dim3 block(256, 1, 1);
    dim3 grid(LIF_HALF / 256, 32, 1);   // 64 x 32 = 2048 blocks
    lif_kernel<<<grid, block, 0, stream>>>(x, y);
}

// Round 7
// 57.392 us; speedup vs baseline: 1.3413x; 1.0339x over previous
//
#include <hip/hip_runtime.h>

// LIF spike recurrence over time axis.
// x: [B=32, T=10, C=128, H=32, W=32] fp32 -> spikes same shape fp32.
// mem_t = tau*mem_{t-1} + x_t; spike = (mem_t > thresh); mem_t <- (1-spike)*mem_t.
//
// R7: occupancy x MLP sweep point: ONE chain per thread, ALL 10 loads
// issued first (40 VGPRs data, ~64-72 total -> 8 waves/SIMD, 2x R6's
// occupancy) while retaining 10 outstanding nt-loads per thread.
// 4096 blocks, per-instruction fully coalesced, nt load/store.

typedef float f32x4 __attribute__((ext_vector_type(4)));

#define LIF_T 10
#define LIF_INNER4 32768       // C*H*W/4 per (b,t) slab, in float4 units
#define LIF_TAU 0.5f
#define LIF_THRESH 1.0f

__global__ void __launch_bounds__(256) lif_kernel(const f32x4* __restrict__ x,
                                                  f32x4* __restrict__ y) {
    const int i = blockIdx.x * blockDim.x + threadIdx.x;   // 0 .. INNER4-1
    const int b = blockIdx.y;
    const size_t base = (size_t)b * LIF_T * LIF_INNER4 + i;

    // ---- phase 1: issue ALL loads (fully unrolled, static indices) ----
    f32x4 xv[LIF_T];
#pragma unroll
    for (int t = 0; t < LIF_T; ++t) {
        xv[t] = __builtin_nontemporal_load(&x[base + (size_t)t * LIF_INNER4]);
    }

    // ---- phase 2: recurrence + stores ----
    f32x4 m = (f32x4)(0.f);
#pragma unroll
    for (int t = 0; t < LIF_T; ++t) {
        m = m * LIF_TAU + xv[t];

        f32x4 s;
        s.x = (m.x > LIF_THRESH) ? 1.f : 0.f;
        s.y = (m.y > LIF_THRESH) ? 1.f : 0.f;
        s.z = (m.z > LIF_THRESH) ? 1.f : 0.f;
        s.w = (m.w > LIF_THRESH) ? 1.f : 0.f;

        __builtin_nontemporal_store(s, &y[base + (size_t)t * LIF_INNER4]);

        m.x = (s.x > 0.f) ? 0.f : m.x;
        m.y = (s.y > 0.f) ? 0.f : m.y;
        m.z = (s.z > 0.f) ? 0.f : m.z;
        m.w = (s.w > 0.f) ? 0.f : m.w;
    }
}

extern "C" void kernel_launch(void* const* d_in, const int* in_sizes, int n_in,
                              void* d_out, int out_size, void* d_ws, size_t ws_size,
                              hipStream_t stream) {
    const f32x4* x = (const f32x4*)d_in[0];
    f32x4* y = (f32x4*)d_out;

    dim3 block(256, 1, 1);
    dim3 grid(LIF_INNER4 / 256, 32, 1);   // 128 x 32 = 4096 blocks
    lif_kernel<<<grid, block, 0, stream>>>(x, y);
}